// Round 10
// baseline (37.406 us; speedup 1.0000x reference)
//
#include <hip/hip_runtime.h>

#define NREL1  12   // NREL + 1 relation matrices
#define NN     128  // neighbours
#define EE     128  // in-features
#define FF     128  // out-features
#define BV     192  // B * V
#define RK     (NREL1 * EE)   // 1536
#define NEDGE  (BV * NN)      // 24576

// ws layout (floats):
//   [0, 3072)               wa  (Wa1[12][128] | Wa2[12][128])
//   [4096, 28672)           e_ws: per-edge logits (leaky applied)
//   [32768, 32768+BV*4*RK)  S4: partial S rows, [(bv*4+q)][RK]
#define WS_WA  0
#define WS_E   4096
#define WS_S4  32768

// K0: wa rows (wave per (r,e), coalesced W read once aggregate) + zero out.
__global__ __launch_bounds__(256) void prep_kernel(const float* __restrict__ W,
                                                   const float* __restrict__ a,
                                                   float* __restrict__ ws,
                                                   float* __restrict__ out) {
    const int w    = blockIdx.x * 4 + (threadIdx.x >> 6);  // 1536 waves
    const int lane = threadIdx.x & 63;
    const int r = w >> 7, e = w & 127;
    const float2 wv = *(const float2*)(W + (size_t)(r * EE + e) * FF + lane * 2);
    const float2 a1 = *(const float2*)(a + lane * 2);
    const float2 a2 = *(const float2*)(a + FF + lane * 2);
    float d1 = wv.x * a1.x + wv.y * a1.y;
    float d2 = wv.x * a2.x + wv.y * a2.y;
#pragma unroll
    for (int off = 32; off; off >>= 1) {
        d1 += __shfl_xor(d1, off);
        d2 += __shfl_xor(d2, off);
    }
    if (lane == 0) {
        ws[WS_WA + r * EE + e]      = d1;
        ws[WS_WA + RK + r * EE + e] = d2;
    }
    const int gid = blockIdx.x * 256 + threadIdx.x;
    if (gid < BV * FF) out[gid] = 0.f;
}

// K1: wave per edge, 6144 blocks x 256. Owns the 25 MB fe+ne HBM stream.
// lanes 0-31 dot ne.wa1, lanes 32-63 dot fe.wa2; 64-lane butterfly; leaky.
__global__ __launch_bounds__(256) void logits_kernel(const float* __restrict__ fe,
                                                     const float* __restrict__ ne,
                                                     const int* __restrict__ widx,
                                                     const float* __restrict__ ws_r,
                                                     float* __restrict__ ws_w) {
    const int wave = threadIdx.x >> 6;
    const int lane = threadIdx.x & 63;
    const int l32  = lane & 31;
    const int half = lane >> 5;
    const int edge = blockIdx.x * 4 + wave;

    const int r = widx[edge];
    const float4 xv = *(const float4*)((half ? fe : ne) + (size_t)edge * EE + l32 * 4);
    const float4 wq = *(const float4*)(ws_r + WS_WA + half * RK + r * EE + l32 * 4);
    float d = xv.x * wq.x + xv.y * wq.y + xv.z * wq.z + xv.w * wq.w;
#pragma unroll
    for (int off = 32; off; off >>= 1) d += __shfl_xor(d, off);
    if (lane == 0) ws_w[WS_E + edge] = d > 0.f ? d : 0.2f * d;
}

// K2: block per (bv, n-quarter): 768 blocks x 256 thr, 48 KB LDS (3 blk/CU).
// Redundant softmax from e_ws (wave 0), then scatter THIS quarter's 32 edges
// into 8 private LDS copies (wave x half), reduce -> partial S row to ws.
__global__ __launch_bounds__(256) void sbuild_kernel(const float* __restrict__ ne,
                                                     const int* __restrict__ widx,
                                                     const float* __restrict__ ind,
                                                     const float* __restrict__ ws_r,
                                                     float* __restrict__ ws_w) {
    __shared__ float s8[8][RK];    // 48 KB
    __shared__ float attn_s[NN];
    __shared__ int   idxq[32];

    const int blk  = blockIdx.x;
    const int bv   = blk >> 2;
    const int q    = blk & 3;
    const int tid  = threadIdx.x;
    const int wave = tid >> 6;
    const int lane = tid & 63;
    const int l32  = lane & 31;
    const int half = lane >> 5;

    if (tid >= 64 && tid < 96) idxq[tid - 64] = widx[bv * NN + q * 32 + (tid - 64)];
    {
        const float4 z = {0.f, 0.f, 0.f, 0.f};
        float4* p = (float4*)&s8[0][0];
#pragma unroll
        for (int i = 0; i < 12; ++i) p[i * 256 + tid] = z;
    }
    // softmax over all 128 neighbours + indicator mask (wave 0)
    if (tid < 64) {
        const float v0 = ws_r[WS_E + bv * NN + tid];
        const float v1 = ws_r[WS_E + bv * NN + tid + 64];
        float m = fmaxf(v0, v1);
#pragma unroll
        for (int off = 32; off; off >>= 1) m = fmaxf(m, __shfl_xor(m, off));
        float ex0 = expf(v0 - m), ex1 = expf(v1 - m);
        float ssum = ex0 + ex1;
#pragma unroll
        for (int off = 32; off; off >>= 1) ssum += __shfl_xor(ssum, off);
        const float inv = 1.f / ssum;
        attn_s[tid]      = ex0 * inv * ind[bv * NN + tid];
        attn_s[tid + 64] = ex1 * inv * ind[bv * NN + tid + 64];
    }
    __syncthreads();

    // scatter this quarter's 32 edges; copy per (wave, half) -> race-free
    {
        const float* ne_bv = ne + (size_t)bv * NN * EE;
        float* sc = s8[wave * 2 + half];
#pragma unroll
        for (int i = 0; i < 4; ++i) {
            const int nl = wave * 8 + i * 2 + half;     // 0..31 within quarter
            const int n  = q * 32 + nl;
            const float an = attn_s[n];
            const int r  = idxq[nl];
            const float4 x = *(const float4*)(ne_bv + (size_t)n * EE + l32 * 4);
            float* p = sc + r * EE + l32 * 4;
            float4 cur = *(const float4*)p;
            cur.x += an * x.x; cur.y += an * x.y;
            cur.z += an * x.z; cur.w += an * x.w;
            *(float4*)p = cur;
        }
    }
    __syncthreads();

    // reduce 8 copies -> partial S row for (bv, q)
    for (int k4 = tid; k4 < RK / 4; k4 += 256) {
        float4 v = {0.f, 0.f, 0.f, 0.f};
#pragma unroll
        for (int c = 0; c < 8; ++c) {
            const float4 t = *(const float4*)&s8[c][k4 * 4];
            v.x += t.x; v.y += t.y; v.z += t.z; v.w += t.w;
        }
        *(float4*)(ws_w + WS_S4 + ((size_t)bv * 4 + q) * RK + k4 * 4) = v;
    }
}

// K3: out[bv0+b][f] += sum_{k in chunk} S[bv0+b][k] * W[k][f]
// grid (12 bv-tiles, 12 K-splits of 128), 256 thr. S = sum of 4 partials,
// folded into the LDS staging reads (all L2-resident).
__global__ __launch_bounds__(256) void gemm_kernel(const float* __restrict__ ws_r,
                                                   const float* __restrict__ W,
                                                   float* __restrict__ out) {
    __shared__ float st[128][20];   // S-chunk transposed [k][b], pad -> free

    const int bv0 = blockIdx.x * 16;
    const int k0  = blockIdx.y * 128;
    const int tid = threadIdx.x;

    // stage S chunk transposed, summing 4 partials
#pragma unroll
    for (int qq = tid; qq < 512; qq += 256) {
        const int b = qq >> 5, kk4 = qq & 31;
        const float* base = ws_r + WS_S4 + (size_t)(bv0 + b) * 4 * RK + k0 + kk4 * 4;
        const float4 v0 = *(const float4*)(base);
        const float4 v1 = *(const float4*)(base + RK);
        const float4 v2 = *(const float4*)(base + 2 * RK);
        const float4 v3 = *(const float4*)(base + 3 * RK);
        st[kk4 * 4 + 0][b] = v0.x + v1.x + v2.x + v3.x;
        st[kk4 * 4 + 1][b] = v0.y + v1.y + v2.y + v3.y;
        st[kk4 * 4 + 2][b] = v0.z + v1.z + v2.z + v3.z;
        st[kk4 * 4 + 3][b] = v0.w + v1.w + v2.w + v3.w;
    }
    __syncthreads();

    const int fq = tid & 31;          // f-quad
    const int bg = (tid >> 5) & 3;    // b-quad
    const int kh = tid >> 7;          // k-half of chunk (64 each)

    float4 acc[4] = {{0,0,0,0},{0,0,0,0},{0,0,0,0},{0,0,0,0}};
    const float* Wp = W + (size_t)(k0 + kh * 64) * FF + fq * 4;

#pragma unroll 4
    for (int k = 0; k < 64; ++k) {
        const float4 w4 = *(const float4*)(Wp + (size_t)k * FF);
        const float* sp = &st[kh * 64 + k][bg * 4];
#pragma unroll
        for (int j = 0; j < 4; ++j) {
            const float sv = sp[j];
            acc[j].x += sv * w4.x; acc[j].y += sv * w4.y;
            acc[j].z += sv * w4.z; acc[j].w += sv * w4.w;
        }
    }

#pragma unroll
    for (int j = 0; j < 4; ++j) {
        float* op = out + (size_t)(bv0 + bg * 4 + j) * FF + fq * 4;
        atomicAdd(op + 0, acc[j].x);
        atomicAdd(op + 1, acc[j].y);
        atomicAdd(op + 2, acc[j].z);
        atomicAdd(op + 3, acc[j].w);
    }
}

extern "C" void kernel_launch(void* const* d_in, const int* in_sizes, int n_in,
                              void* d_out, int out_size, void* d_ws, size_t ws_size,
                              hipStream_t stream) {
    const float* fe  = (const float*)d_in[0];  // feature_embed   (B,V,N,E)
    const float* ne  = (const float*)d_in[1];  // neighbour_embed (B,V,N,E)
    const int*   wi  = (const int*)d_in[2];    // w_index (B,V,N)
    const float* ind = (const float*)d_in[3];  // indicator (B,V,N)
    const float* W   = (const float*)d_in[4];  // (12,E,F)
    const float* a   = (const float*)d_in[5];  // (2F,1)
    float* out = (float*)d_out;                // (B,V,F)
    float* ws  = (float*)d_ws;

    prep_kernel<<<RK / 4, 256, 0, stream>>>(W, a, ws, out);
    logits_kernel<<<NEDGE / 4, 256, 0, stream>>>(fe, ne, wi, ws, ws);
    sbuild_kernel<<<BV * 4, 256, 0, stream>>>(ne, wi, ind, ws, ws);
    gemm_kernel<<<dim3(12, 12), 256, 0, stream>>>(ws, W, out);
}

// Round 11
// 26.342 us; speedup vs baseline: 1.4200x; 1.4200x over previous
//
#include <hip/hip_runtime.h>

#define NREL1  12   // NREL + 1 relation matrices
#define NN     128  // neighbours
#define EE     128  // in-features
#define FF     128  // out-features
#define BV     192  // B * V
#define RK     (NREL1 * EE)   // 1536

// ws layout (floats): [0, 3072) wa (Wa1[12][128] | Wa2[12][128])
#define WS_WA  0

// K0: wa rows (wave per (r,e), coalesced W read once aggregate).
__global__ __launch_bounds__(256) void prep_kernel(const float* __restrict__ W,
                                                   const float* __restrict__ a,
                                                   float* __restrict__ ws) {
    const int w    = blockIdx.x * 4 + (threadIdx.x >> 6);  // 1536 waves
    const int lane = threadIdx.x & 63;
    const int r = w >> 7, e = w & 127;
    const float2 wv = *(const float2*)(W + (size_t)(r * EE + e) * FF + lane * 2);
    const float2 a1 = *(const float2*)(a + lane * 2);
    const float2 a2 = *(const float2*)(a + FF + lane * 2);
    float d1 = wv.x * a1.x + wv.y * a1.y;
    float d2 = wv.x * a2.x + wv.y * a2.y;
#pragma unroll
    for (int off = 32; off; off >>= 1) {
        d1 += __shfl_xor(d1, off);
        d2 += __shfl_xor(d2, off);
    }
    if (lane == 0) {
        ws[WS_WA + r * EE + e]      = d1;
        ws[WS_WA + RK + r * EE + e] = d2;
    }
}

// K1: block per bv, 1024 threads (16 waves). Everything else fused.
// prefetch 8 edges/wave to regs -> logits -> softmax+mask -> scatter into
// per-wave LDS copy -> reduce 16 copies into S (stays in LDS) ->
// Phase D: out[bv] = S @ W  (thread = kg x fq, W from L2, plain stores).
__global__ __launch_bounds__(1024) void gat_fused(const float* __restrict__ fe,
                                                  const float* __restrict__ ne,
                                                  const int* __restrict__ widx,
                                                  const float* __restrict__ ind,
                                                  const float* __restrict__ W,
                                                  const float* __restrict__ ws_r,
                                                  float* __restrict__ out) {
    __shared__ float wa[2 * RK];     // 12 KB
    __shared__ float s16[16][RK];    // 96 KB; s16[0] holds S after reduce
    __shared__ float red[32][FF];    // 16 KB
    __shared__ float red2[4][FF];    // 2 KB
    __shared__ float e_lds[NN];
    __shared__ float attn_s[NN];
    __shared__ int   idx[NN];

    const int bv   = blockIdx.x;
    const int tid  = threadIdx.x;
    const int wave = tid >> 6;
    const int lane = tid & 63;
    const int l32  = lane & 31;
    const int half = lane >> 5;   // 0: ne/wa1 side, 1: fe/wa2 side

    const float* ne_bv = ne + (size_t)bv * NN * EE;
    const float* fe_bv = fe + (size_t)bv * NN * EE;

    if (tid < NN) idx[tid] = widx[bv * NN + tid];

    // prefetch: 8 edges per wave, lane holds one e-quad of ne (or fe)
    float4 xr[8];
    {
        const float* base = (half ? fe_bv : ne_bv) + l32 * 4;
#pragma unroll
        for (int i = 0; i < 8; ++i)
            xr[i] = *(const float4*)(base + (wave * 8 + i) * EE);
    }

    // stage wa (L2) -> LDS (1 float4/thread); zero scatter copies (6/thread)
    if (tid < 2 * RK / 4)
        ((float4*)wa)[tid] = ((const float4*)(ws_r + WS_WA))[tid];
    {
        const float4 z = {0.f, 0.f, 0.f, 0.f};
#pragma unroll
        for (int q = 0; q < 6; ++q)
            ((float4*)&s16[0][0])[q * 1024 + tid] = z;
    }
    __syncthreads();

    // Phase A: logits; lanes<32 contribute ne.wa1, lanes>=32 fe.wa2
#pragma unroll
    for (int i = 0; i < 8; ++i) {
        const int n = wave * 8 + i;
        const int r = idx[n];
        const float4 wq = *(const float4*)&wa[half * RK + r * EE + l32 * 4];
        float d = xr[i].x * wq.x + xr[i].y * wq.y + xr[i].z * wq.z + xr[i].w * wq.w;
#pragma unroll
        for (int off = 32; off; off >>= 1) d += __shfl_xor(d, off);
        if (lane == 0) e_lds[n] = d > 0.f ? d : 0.2f * d;
    }
    __syncthreads();

    // Phase B: softmax over neighbours + indicator mask (wave 0)
    if (tid < 64) {
        float v0 = e_lds[tid], v1 = e_lds[tid + 64];
        float m = fmaxf(v0, v1);
#pragma unroll
        for (int off = 32; off; off >>= 1) m = fmaxf(m, __shfl_xor(m, off));
        float ex0 = expf(v0 - m), ex1 = expf(v1 - m);
        float ssum = ex0 + ex1;
#pragma unroll
        for (int off = 32; off; off >>= 1) ssum += __shfl_xor(ssum, off);
        float inv = 1.f / ssum;
        attn_s[tid]      = ex0 * inv * ind[bv * NN + tid];
        attn_s[tid + 64] = ex1 * inv * ind[bv * NN + tid + 64];
    }
    __syncthreads();

    // Phase C: scatter from regs into this wave's private copy (ne lanes)
    if (half == 0) {
        float* sc = s16[wave];
#pragma unroll
        for (int i = 0; i < 8; ++i) {
            const int n = wave * 8 + i;
            const float an = attn_s[n];
            float* p = sc + idx[n] * EE + l32 * 4;
            float4 cur = *(const float4*)p;
            cur.x += an * xr[i].x; cur.y += an * xr[i].y;
            cur.z += an * xr[i].z; cur.w += an * xr[i].w;
            *(float4*)p = cur;
        }
    }
    __syncthreads();

    // reduce 16 copies -> S in s16[0] (in place)
    if (tid < RK / 4) {
        float4 v = *(const float4*)&s16[0][tid * 4];
#pragma unroll
        for (int c = 1; c < 16; ++c) {
            const float4 t = *(const float4*)&s16[c][tid * 4];
            v.x += t.x; v.y += t.y; v.z += t.z; v.w += t.w;
        }
        *(float4*)&s16[0][tid * 4] = v;
    }
    __syncthreads();

    // Phase D: out[bv][f] = sum_k S[k] * W[k][f]
    // thread = (kg 0..31 owns 48 k's, fq 0..31 owns 4 f). W from L2.
    {
        const int fq = tid & 31;
        const int kg = tid >> 5;
        float4 acc = {0.f, 0.f, 0.f, 0.f};
        const float* Wp = W + (size_t)(kg * 48) * FF + fq * 4;
        const float* Sp = &s16[0][kg * 48];
#pragma unroll 4
        for (int j = 0; j < 48; ++j) {
            const float sv = Sp[j];
            const float4 w4 = *(const float4*)(Wp + (size_t)j * FF);
            acc.x += sv * w4.x; acc.y += sv * w4.y;
            acc.z += sv * w4.z; acc.w += sv * w4.w;
        }
        *(float4*)&red[kg][fq * 4] = acc;
    }
    __syncthreads();
    if (tid < 512) {
        const int f = tid & 127, h = tid >> 7;
        float v = 0.f;
#pragma unroll
        for (int j = 0; j < 8; ++j) v += red[h * 8 + j][f];
        red2[h][f] = v;
    }
    __syncthreads();
    if (tid < FF)
        out[bv * FF + tid] = red2[0][tid] + red2[1][tid] + red2[2][tid] + red2[3][tid];
}

extern "C" void kernel_launch(void* const* d_in, const int* in_sizes, int n_in,
                              void* d_out, int out_size, void* d_ws, size_t ws_size,
                              hipStream_t stream) {
    const float* fe  = (const float*)d_in[0];  // feature_embed   (B,V,N,E)
    const float* ne  = (const float*)d_in[1];  // neighbour_embed (B,V,N,E)
    const int*   wi  = (const int*)d_in[2];    // w_index (B,V,N)
    const float* ind = (const float*)d_in[3];  // indicator (B,V,N)
    const float* W   = (const float*)d_in[4];  // (12,E,F)
    const float* a   = (const float*)d_in[5];  // (2F,1)
    float* out = (float*)d_out;                // (B,V,F)
    float* ws  = (float*)d_ws;

    prep_kernel<<<RK / 4, 256, 0, stream>>>(W, a, ws);
    gat_fused<<<BV, 1024, 0, stream>>>(fe, ne, wi, ind, W, ws, out);
}